// Round 5
// baseline (243.345 us; speedup 1.0000x reference)
//
#include <hip/hip_runtime.h>
#include <hip/hip_bf16.h>

// KAN layer = GEMM: out[b,o] = sum_{i,k} T_k(tanh(x[b,i])) * W[o,i,k] + bias[o]
// FUSED v4: A never materialized, never in LDS (per-lane A-fragment = cheb8 of
// one feature straight into registers). Triple-buffered B via global_load_lds,
// one s_barrier per K-step, counted vmcnt.
// v4 fixes v3's correctness bug: the counted wait must equal the VMEM ops per
// region between waits (8 here: 4 stage + 4 x). v3's vmcnt(12) let stage(T)
// survive the wait under compiler reordering of x vs stage issues -> stale LDS
// reads. v4: vmcnt(8) steady state; x-prefetch issued post-barrier; ITER(0)
// does a full vmcnt(0) drain because the prologue region has 12 ops.
#define MD 4096
#define ND 1024
#define KD 8192
#define IN_F 1024

typedef __bf16 bf16x8 __attribute__((ext_vector_type(8)));
typedef float f32x4 __attribute__((ext_vector_type(4)));

// ---------------- Pass 1: W fp32 -> bf16 (48 MB traffic, ~10 us) ----------
#define N_CONV ((ND * KD) / 8)

__global__ __launch_bounds__(256) void conv_kernel(
    const float* __restrict__ w, __bf16* __restrict__ B) {
  int j = blockIdx.x * blockDim.x + threadIdx.x;  // grid is exact, no tail
  const float4* p = (const float4*)(w + (size_t)j * 8);
  float4 a = p[0], b = p[1];
  bf16x8 v;
  v[0] = (__bf16)a.x; v[1] = (__bf16)a.y; v[2] = (__bf16)a.z; v[3] = (__bf16)a.w;
  v[4] = (__bf16)b.x; v[5] = (__bf16)b.y; v[6] = (__bf16)b.z; v[7] = (__bf16)b.w;
  *(bf16x8*)(B + (size_t)j * 8) = v;
}

// ---------------- Pass 2: fused basis + GEMM_BT + bias ----------------
#define BM 64
#define BN 128
#define BK 64
#define NT (KD / BK)      // 128 K-steps
#define BUFSZ (BN * BK)   // 8192 bf16 = 16 KB per buffer

__device__ __forceinline__ bf16x8 cheb8(float xs) {
  // fast tanh: copysign(1 - 2/(exp2(2*log2(e)*|x|) + 1), x); |err| ~1e-7.
  float ax = __builtin_fabsf(xs);
  float e = __builtin_amdgcn_exp2f(ax * 2.88539008177792681472f);
  float r = __builtin_amdgcn_rcpf(e + 1.0f);
  float t = 1.0f - 2.0f * r;
  t = __builtin_copysignf(t, xs);
  float two_t = 2.0f * t;
  float T0 = 1.0f;
  float T1 = t;
  float T2 = two_t * T1 - T0;
  float T3 = two_t * T2 - T1;
  float T4 = two_t * T3 - T2;
  float T5 = two_t * T4 - T3;
  float T6 = two_t * T5 - T4;
  float T7 = two_t * T6 - T5;
  bf16x8 v;
  v[0] = (__bf16)T0; v[1] = (__bf16)T1; v[2] = (__bf16)T2; v[3] = (__bf16)T3;
  v[4] = (__bf16)T4; v[5] = (__bf16)T5; v[6] = (__bf16)T6; v[7] = (__bf16)T7;
  return v;
}

__global__ __launch_bounds__(256) void gemm_bias(
    const float* __restrict__ x, const __bf16* __restrict__ B,
    const float* __restrict__ bias, float* __restrict__ C) {
  __shared__ __align__(16) __bf16 Bs[3 * BUFSZ];  // 48 KB

  const int tid = threadIdx.x;
  const int wave = tid >> 6;
  const int lane = tid & 63;
  const int n0 = blockIdx.x * BN;   // gridDim.x == 8 == NXCD: each XCD keeps
  const int m0 = blockIdx.y * BM;   // its own 2 MB B-panel L2-resident.
  const int wm = wave >> 1;   // 0..1
  const int wn = wave & 1;    // 0..1

  // ---- B staging: one global_load_lds (16B/lane) covers 8 rows of 128B.
  // XOR swizzle applied on the GLOBAL address side (LDS dst must be linear).
  const int ar = lane >> 3;                  // 0..7
  const int swz_col = ((lane & 7) ^ ar) * 8;
  const __bf16* gB = B + (size_t)(n0 + wave * 32 + ar) * KD + swz_col;
  const int lBoff = (wave * 32) * BK;

  // ---- fragment coords (16x16x32: row=lane&15, k=(lane>>4)*8+j)
  const int fr = lane & 15;
  const int fr7 = fr & 7;
  const int qk = lane >> 4;  // 0..3

  // ---- x pointers: lane owns rows (wm*32+fr) and (+16); feature f = 8t+s*4+qk
  const float* xr0 = x + (size_t)(m0 + wm * 32 + fr) * IN_F + qk;
  const float* xr1 = xr0 + 16 * IN_F;

  f32x4 acc[2][4];
#pragma unroll
  for (int i = 0; i < 2; i++)
#pragma unroll
    for (int j = 0; j < 4; j++) acc[i][j] = (f32x4){0.f, 0.f, 0.f, 0.f};

  // ---- prologue: stage(0) -> buf0; x(0), x(1) into regs (distance 2)
#pragma unroll
  for (int j = 0; j < 4; j++)
    __builtin_amdgcn_global_load_lds(
        (const __attribute__((address_space(1))) void*)(gB + (size_t)j * 8 * KD),
        (__attribute__((address_space(3))) void*)(Bs + lBoff + j * 8 * BK), 16, 0, 0);
  float xa0 = xr0[0], xa1 = xr0[4], xa2 = xr1[0], xa3 = xr1[4];
  float xb0 = xr0[8], xb1 = xr0[12], xb2 = xr1[8], xb3 = xr1[12];

  // Per iter T (compile-time buffer indices CUR/NXT):
  //   pre-barrier : stage(T+1)->buf[NXT]; cheb8 on x(T); WAIT; s_barrier
  //   post-barrier: issue x(T+2) loads; ds_read buf[CUR]; 16 MFMA
  // Region invariant: exactly 8 VMEM ops (4 stage + 4 x) issue between
  // consecutive WAITs, so vmcnt(8) always drains stage(T) and everything
  // older, regardless of intra-region compiler reordering. ITER(0) uses
  // vmcnt(0) because the prologue region holds 12 ops (stage(0)+x(0)+x(1)).
  // Skew safety (1 barrier, 3 buffers): between barrier T and T+1 the only
  // LDS writes target buf[(T+2)%3]; reads target buf[T%3].
#define ITER(T, CUR, NXT, WAIT)                                                \
  do {                                                                         \
    const int tn = ((T) + 1 < NT) ? (T) + 1 : 0;                               \
    const int tx = ((T) + 2 < NT) ? (T) + 2 : 0;                               \
    _Pragma("unroll") for (int j = 0; j < 4; j++)                              \
        __builtin_amdgcn_global_load_lds(                                      \
            (const __attribute__((address_space(1))) void*)(                   \
                gB + (size_t)tn * BK + (size_t)j * 8 * KD),                    \
            (__attribute__((address_space(3))) void*)(                         \
                Bs + (NXT)*BUFSZ + lBoff + j * 8 * BK),                        \
            16, 0, 0);                                                         \
    bf16x8 a00 = cheb8(xa0), a01 = cheb8(xa1);                                 \
    bf16x8 a10 = cheb8(xa2), a11 = cheb8(xa3);                                 \
    asm volatile(WAIT ::: "memory");                                           \
    __builtin_amdgcn_s_barrier();                                              \
    asm volatile("" ::: "memory");                                             \
    __builtin_amdgcn_sched_barrier(0);                                         \
    float xn0 = xr0[tx * 8], xn1 = xr0[tx * 8 + 4];                            \
    float xn2 = xr1[tx * 8], xn3 = xr1[tx * 8 + 4];                            \
    const __bf16* lB = Bs + (CUR)*BUFSZ;                                       \
    _Pragma("unroll") for (int s = 0; s < 2; s++) {                            \
      const int pa = ((s * 4 + qk) ^ fr7) * 8;                                 \
      bf16x8 bfr[4];                                                           \
      _Pragma("unroll") for (int ni = 0; ni < 4; ni++)                         \
          bfr[ni] = *(const bf16x8*)&lB[(wn * 64 + ni * 16 + fr) * BK + pa];   \
      bf16x8 af0 = s ? a01 : a00;                                              \
      bf16x8 af1 = s ? a11 : a10;                                              \
      _Pragma("unroll") for (int ni = 0; ni < 4; ni++) {                       \
        acc[0][ni] = __builtin_amdgcn_mfma_f32_16x16x32_bf16(af0, bfr[ni],     \
                                                             acc[0][ni], 0, 0, 0); \
        acc[1][ni] = __builtin_amdgcn_mfma_f32_16x16x32_bf16(af1, bfr[ni],     \
                                                             acc[1][ni], 0, 0, 0); \
      }                                                                        \
    }                                                                          \
    xa0 = xb0; xa1 = xb1; xa2 = xb2; xa3 = xb3;                                \
    xb0 = xn0; xb1 = xn1; xb2 = xn2; xb3 = xn3;                                \
  } while (0)

  ITER(0, 0, 1, "s_waitcnt vmcnt(0)");   // prologue drain (12-op region)
  ITER(1, 1, 2, "s_waitcnt vmcnt(8)");
  ITER(2, 2, 0, "s_waitcnt vmcnt(8)");
  for (int t0 = 3; t0 < 126; t0 += 3) {  // iters 3..125, phase static
    ITER(t0, 0, 1, "s_waitcnt vmcnt(8)");
    ITER(t0 + 1, 1, 2, "s_waitcnt vmcnt(8)");
    ITER(t0 + 2, 2, 0, "s_waitcnt vmcnt(8)");
  }
  ITER(126, 0, 1, "s_waitcnt vmcnt(8)");
  ITER(127, 1, 2, "s_waitcnt vmcnt(8)");
#undef ITER

  // ---- epilogue: C/D layout col=lane&15, row=(lane>>4)*4+r ; add bias
  const int col0 = n0 + wn * 64;
  const int row0 = m0 + wm * 32 + (lane >> 4) * 4;
#pragma unroll
  for (int ni = 0; ni < 4; ni++) {
    int col = col0 + ni * 16 + (lane & 15);
    float bv = bias[col];
#pragma unroll
    for (int mi = 0; mi < 2; mi++) {
      int row = row0 + mi * 16;
#pragma unroll
      for (int r = 0; r < 4; r++)
        C[(size_t)(row + r) * ND + col] = acc[mi][ni][r] + bv;
    }
  }
}

extern "C" void kernel_launch(void* const* d_in, const int* in_sizes, int n_in,
                              void* d_out, int out_size, void* d_ws, size_t ws_size,
                              hipStream_t stream) {
  const float* x = (const float*)d_in[0];     // [4096,1024]
  const float* w = (const float*)d_in[1];     // [1024,1024,8]
  const float* bias = (const float*)d_in[2];  // [1024]
  float* out = (float*)d_out;                 // [4096,1024]

  __bf16* Bbf = (__bf16*)d_ws;  // 1024*8192 bf16 = 16 MB

  conv_kernel<<<N_CONV / 256, 256, 0, stream>>>(w, Bbf);

  dim3 grid(ND / BN, MD / BM);  // (8, 64) = 512 blocks -> 2 blocks/CU
  gemm_bias<<<grid, 256, 0, stream>>>(x, Bbf, bias, out);
}